// Round 8
// baseline (137.422 us; speedup 1.0000x reference)
//
#include <hip/hip_runtime.h>
#include <math.h>

#define H 2048
#define L 350
#define NB 512

// ws float offsets
#define OFF_GH   512
#define OFF_G    7168
#define OFF_CTX  9216
#define OFF_CNT  12288

// counter indices
#define W_LOG 0
#define D_LOG 1
#define W_GH  2
#define D_GH  3
#define W_CTX 4
#define D_CTX 5
#define W_CMB 6
#define D_CMB 7
#define W_GRU 8

#define VMCNT0() asm volatile("s_waitcnt vmcnt(0)" ::: "memory")

__device__ __forceinline__ float cload(const float* p) {
    return __hip_atomic_load(p, __ATOMIC_RELAXED, __HIP_MEMORY_SCOPE_AGENT);
}
__device__ __forceinline__ void cstore(float* p, float v) {
    __hip_atomic_store(p, v, __ATOMIC_RELAXED, __HIP_MEMORY_SCOPE_AGENT);
}
__device__ __forceinline__ unsigned iadd(unsigned* p, unsigned v) {
    return __hip_atomic_fetch_add(p, v, __ATOMIC_RELAXED, __HIP_MEMORY_SCOPE_AGENT);
}

__device__ __forceinline__ float dot4(float4 a, float4 b, float acc) {
    acc = fmaf(a.x, b.x, acc);
    acc = fmaf(a.y, b.y, acc);
    acc = fmaf(a.z, b.z, acc);
    acc = fmaf(a.w, b.w, acc);
    return acc;
}
__device__ __forceinline__ float wsum(float v) {
    #pragma unroll
    for (int m = 1; m < 64; m <<= 1) v += __shfl_xor(v, m, 64);
    return v;
}
__device__ __forceinline__ float wmax(float v) {
    #pragma unroll
    for (int m = 1; m < 64; m <<= 1) v = fmaxf(v, __shfl_xor(v, m, 64));
    return v;
}

__global__ __launch_bounds__(256, 2) void fused_decoder(
    const float* __restrict__ input, const float* __restrict__ hidden,
    const float* __restrict__ enc,
    const float* __restrict__ attn_W, const float* __restrict__ attn_b,
    const float* __restrict__ comb_W, const float* __restrict__ comb_b,
    const float* __restrict__ w_ih, const float* __restrict__ w_hh,
    const float* __restrict__ b_ih, const float* __restrict__ b_hh,
    float* __restrict__ out, float* __restrict__ ws)
{
    __shared__ __align__(16) float sh[2048];
    __shared__ float smax[4], ssum[4];
    __shared__ float part[8][32];
    __shared__ unsigned claim_s, done_s;

    float* logits = ws;
    float* gh     = ws + OFF_GH;
    float* g      = ws + OFF_G;
    float* ctx    = ws + OFF_CTX;
    unsigned* cnt = (unsigned*)(ws + OFF_CNT);

    const int tid = threadIdx.x, wv = tid >> 6, lane = tid & 63;
    const float4* x4 = reinterpret_cast<const float4*>(input);
    const float4* h4 = reinterpret_cast<const float4*>(hidden);

    // ---------------- P1: logits pool (chunks of 4 rows, 1 row/wave) -------
    for (;;) {
        __syncthreads();
        if (tid == 0) claim_s = iadd(&cnt[W_LOG], 4);
        __syncthreads();
        const unsigned r0 = claim_s;
        if (r0 >= L) break;
        const unsigned r = r0 + wv;
        if (r < L) {
            const float4* Wr = reinterpret_cast<const float4*>(attn_W + (size_t)r * (2 * H));
            float acc = 0.f;
            #pragma unroll
            for (int i = lane; i < H / 4; i += 64) {
                acc = dot4(Wr[i], x4[i], acc);
                acc = dot4(Wr[H / 4 + i], h4[i], acc);
            }
            acc = wsum(acc);
            if (lane == 0) cstore(&logits[r], acc + attn_b[r]);
        }
        VMCNT0();
        __syncthreads();
        if (tid == 0) iadd(&cnt[D_LOG], 4);
    }

    // ---------------- P2: wait logits done (352), gh chunks as filler ------
    for (;;) {
        __syncthreads();
        if (tid == 0) {
            done_s = (iadd(&cnt[D_LOG], 0) >= 352u) ? 1u : 0u;
            claim_s = done_s ? 0xFFFFFFFFu : iadd(&cnt[W_GH], 16);
        }
        __syncthreads();
        if (done_s) break;
        const unsigned base = claim_s;
        if (base < 3 * H) {
            const unsigned r0 = base + wv * 4;
            for (unsigned r = r0; r < r0 + 4; ++r) {
                const float4* Wr = reinterpret_cast<const float4*>(w_hh + (size_t)r * H);
                float acc = 0.f;
                #pragma unroll
                for (int i = lane; i < H / 4; i += 64) acc = dot4(Wr[i], h4[i], acc);
                acc = wsum(acc);
                if (lane == 0) cstore(&gh[r], acc + b_hh[r]);
            }
            VMCNT0();
            __syncthreads();
            if (tid == 0) iadd(&cnt[D_GH], 16);
        } else {
            if (tid == 0) __builtin_amdgcn_s_sleep(4);
        }
    }

    // ---------------- P3: block-local softmax -> sh[0..349] (deterministic)
    {
        float v0 = (tid < L) ? cload(&logits[tid]) : -INFINITY;
        float v1 = (tid + 256 < L) ? cload(&logits[tid + 256]) : -INFINITY;
        float m = wmax(fmaxf(v0, v1));
        if (lane == 0) smax[wv] = m;
        __syncthreads();
        m = fmaxf(fmaxf(smax[0], smax[1]), fmaxf(smax[2], smax[3]));
        float e0 = (tid < L) ? expf(v0 - m) : 0.f;
        float e1 = (tid + 256 < L) ? expf(v1 - m) : 0.f;
        float s = wsum(e0 + e1);
        if (lane == 0) ssum[wv] = s;
        __syncthreads();
        const float inv = 1.f / (ssum[0] + ssum[1] + ssum[2] + ssum[3]);
        if (tid < L) sh[tid] = e0 * inv;
        if (tid + 256 < L) sh[tid + 256] = e1 * inv;
        __syncthreads();
    }

    // ---------------- P4: ctx pool (block items of 32 cols, 64 items) ------
    for (;;) {
        __syncthreads();
        if (tid == 0) claim_s = iadd(&cnt[W_CTX], 1);
        __syncthreads();
        const unsigned item = claim_s;
        if (item >= 64) break;
        if (item == 0) {   // attn_weights output (bitwise-identical in any block)
            if (tid < L) out[2 * H + tid] = sh[tid];
            if (tid + 256 < L) out[2 * H + tid + 256] = sh[tid + 256];
        }
        const int col_l = tid & 31, k = tid >> 5;
        const int col = item * 32 + col_l;
        const float* ec = enc + col;
        float a0 = 0.f, a1 = 0.f, a2 = 0.f, a3 = 0.f;
        int j = k;
        for (; j + 24 < L; j += 32) {
            a0 = fmaf(sh[j],      ec[(size_t)j * H],        a0);
            a1 = fmaf(sh[j + 8],  ec[(size_t)(j + 8) * H],  a1);
            a2 = fmaf(sh[j + 16], ec[(size_t)(j + 16) * H], a2);
            a3 = fmaf(sh[j + 24], ec[(size_t)(j + 24) * H], a3);
        }
        for (; j < L; j += 8) a0 = fmaf(sh[j], ec[(size_t)j * H], a0);
        part[k][col_l] = (a0 + a1) + (a2 + a3);
        __syncthreads();
        if (tid < 32) {
            float acc = 0.f;
            #pragma unroll
            for (int kk = 0; kk < 8; ++kk) acc += part[kk][tid];
            cstore(&ctx[item * 32 + tid], acc);
        }
        VMCNT0();
        __syncthreads();
        if (tid == 0) iadd(&cnt[D_CTX], 1);
    }

    // ---------------- P5: gh pool drain (chunks of 16 rows, 4/wave) --------
    for (;;) {
        __syncthreads();
        if (tid == 0) claim_s = iadd(&cnt[W_GH], 16);
        __syncthreads();
        const unsigned base = claim_s;
        if (base >= 3 * H) break;
        const unsigned r0 = base + wv * 4;
        for (unsigned r = r0; r < r0 + 4; ++r) {
            const float4* Wr = reinterpret_cast<const float4*>(w_hh + (size_t)r * H);
            float acc = 0.f;
            #pragma unroll
            for (int i = lane; i < H / 4; i += 64) acc = dot4(Wr[i], h4[i], acc);
            acc = wsum(acc);
            if (lane == 0) cstore(&gh[r], acc + b_hh[r]);
        }
        VMCNT0();
        __syncthreads();
        if (tid == 0) iadd(&cnt[D_GH], 16);
    }

    // ---------------- P6: wait ctx done (bounded), stage ctx -> sh ---------
    if (tid == 0) {
        for (int it = 0; it < (1 << 24); ++it) {
            if (iadd(&cnt[D_CTX], 0) >= 64u) break;
            __builtin_amdgcn_s_sleep(4);
        }
    }
    __syncthreads();
    for (int i = tid; i < H; i += 256) sh[i] = cload(&ctx[i]);
    __syncthreads();

    // ---------------- P7: combine pool (chunks of 8 rows, 2/wave) ----------
    {
        const float4* c4 = reinterpret_cast<const float4*>(sh);
        for (;;) {
            __syncthreads();
            if (tid == 0) claim_s = iadd(&cnt[W_CMB], 8);
            __syncthreads();
            const unsigned base = claim_s;
            if (base >= H) break;
            const unsigned r0 = base + wv * 2;
            for (unsigned r = r0; r < r0 + 2; ++r) {
                const float4* Wr = reinterpret_cast<const float4*>(comb_W + (size_t)r * (2 * H));
                float acc = 0.f;
                #pragma unroll
                for (int i = lane; i < H / 4; i += 64) {
                    acc = dot4(Wr[i], x4[i], acc);
                    acc = dot4(Wr[H / 4 + i], c4[i], acc);
                }
                acc = wsum(acc);
                if (lane == 0) cstore(&g[r], fmaxf(acc + comb_b[r], 0.f));
            }
            VMCNT0();
            __syncthreads();
            if (tid == 0) iadd(&cnt[D_CMB], 8);
        }
    }

    // ---------------- P8: wait combine+gh done (bounded), stage g -> sh ----
    if (tid == 0) {
        for (int it = 0; it < (1 << 24); ++it) {
            if (iadd(&cnt[D_CMB], 0) >= (unsigned)H &&
                iadd(&cnt[D_GH], 0) >= (unsigned)(3 * H)) break;
            __builtin_amdgcn_s_sleep(4);
        }
    }
    __syncthreads();
    for (int i = tid; i < H; i += 256) sh[i] = cload(&g[i]);
    __syncthreads();

    // ---------------- P9: gru pool (chunks of 8 cols, 2/wave) --------------
    {
        const float4* g4 = reinterpret_cast<const float4*>(sh);
        for (;;) {
            __syncthreads();
            if (tid == 0) claim_s = iadd(&cnt[W_GRU], 8);
            __syncthreads();
            const unsigned base = claim_s;
            if (base >= H) break;
            const unsigned c0 = base + wv * 2;
            for (unsigned col = c0; col < c0 + 2; ++col) {
                const float4* Wr0 = reinterpret_cast<const float4*>(w_ih + (size_t)col * H);
                const float4* Wr1 = reinterpret_cast<const float4*>(w_ih + (size_t)(col + H) * H);
                const float4* Wr2 = reinterpret_cast<const float4*>(w_ih + (size_t)(col + 2 * H) * H);
                float ar = 0.f, az = 0.f, an = 0.f;
                #pragma unroll
                for (int i = lane; i < H / 4; i += 64) {
                    const float4 gv = g4[i];
                    ar = dot4(Wr0[i], gv, ar);
                    az = dot4(Wr1[i], gv, az);
                    an = dot4(Wr2[i], gv, an);
                }
                ar = wsum(ar); az = wsum(az); an = wsum(an);
                if (lane == 0) {
                    const float ir  = ar + b_ih[col];
                    const float iz  = az + b_ih[col + H];
                    const float in_ = an + b_ih[col + 2 * H];
                    const float hr = cload(&gh[col]);
                    const float hz = cload(&gh[col + H]);
                    const float hn = cload(&gh[col + 2 * H]);
                    const float r = 1.f / (1.f + expf(-(ir + hr)));
                    const float z = 1.f / (1.f + expf(-(iz + hz)));
                    const float n = tanhf(in_ + r * hn);
                    const float hnew = (1.f - z) * n + z * hidden[col];
                    out[col] = hnew;
                    out[H + col] = hnew;
                }
            }
        }
    }
}

extern "C" void kernel_launch(void* const* d_in, const int* in_sizes, int n_in,
                              void* d_out, int out_size, void* d_ws, size_t ws_size,
                              hipStream_t stream)
{
    const float* input  = (const float*)d_in[0];
    const float* hidden = (const float*)d_in[1];
    const float* enc    = (const float*)d_in[2];
    const float* attn_W = (const float*)d_in[3];
    const float* attn_b = (const float*)d_in[4];
    const float* comb_W = (const float*)d_in[5];
    const float* comb_b = (const float*)d_in[6];
    const float* w_ih   = (const float*)d_in[7];
    const float* w_hh   = (const float*)d_in[8];
    const float* b_ih   = (const float*)d_in[9];
    const float* b_hh   = (const float*)d_in[10];
    float* out = (float*)d_out;
    float* ws  = (float*)d_ws;

    // all pool/done counters must start at zero
    hipMemsetAsync(ws + OFF_CNT, 0, 64, stream);

    fused_decoder<<<NB, 256, 0, stream>>>(
        input, hidden, enc, attn_W, attn_b, comb_W, comb_b,
        w_ih, w_hh, b_ih, b_hh, out, ws);
}

// Round 9
// 64.702 us; speedup vs baseline: 2.1239x; 2.1239x over previous
//
#include <hip/hip_runtime.h>
#include <math.h>

#define H 2048
#define L 350
#define NB 512
#define NLOG 88            // blocks 0..87: 4 logit rows each (352 >= 350)
#define NCTX 64            // blocks 88..151: 32 ctx cols each
// blocks 152..511: main gh blocks (15 rows each = 5400)

// ws float offsets
#define OFF_GH   512
#define OFF_G    7168
#define OFF_CTX  9216
#define OFF_CNT  12288

// counter uint indices — each on its own 256B slot
#define C_LOG 0
#define C_CTX 64
#define C_CMB 128
#define C_GH  192

#define VMCNT0() asm volatile("s_waitcnt vmcnt(0)" ::: "memory")

// ---- data path (R8-proven coherent cross-XCD) ----
__device__ __forceinline__ float cload(const float* p) {
    return __hip_atomic_load(p, __ATOMIC_RELAXED, __HIP_MEMORY_SCOPE_AGENT);
}
__device__ __forceinline__ void cstore(float* p, float v) {
    __hip_atomic_store(p, v, __ATOMIC_RELAXED, __HIP_MEMORY_SCOPE_AGENT);
}
__device__ __forceinline__ unsigned long long cload64(const unsigned long long* p) {
    return __hip_atomic_load(p, __ATOMIC_RELAXED, __HIP_MEMORY_SCOPE_AGENT);
}
// ---- sync path: SYSTEM-scope posts (RMW) + SYSTEM-scope load polls ----
__device__ __forceinline__ void post(unsigned* p) {
    __hip_atomic_fetch_add(p, 1u, __ATOMIC_RELAXED, __HIP_MEMORY_SCOPE_SYSTEM);
}
__device__ __forceinline__ unsigned peek(const unsigned* p) {
    return __hip_atomic_load(p, __ATOMIC_RELAXED, __HIP_MEMORY_SCOPE_SYSTEM);
}

__device__ __forceinline__ float dot4(float4 a, float4 b, float acc) {
    acc = fmaf(a.x, b.x, acc);
    acc = fmaf(a.y, b.y, acc);
    acc = fmaf(a.z, b.z, acc);
    acc = fmaf(a.w, b.w, acc);
    return acc;
}
__device__ __forceinline__ float wsum(float v) {
    #pragma unroll
    for (int m = 1; m < 64; m <<= 1) v += __shfl_xor(v, m, 64);
    return v;
}
__device__ __forceinline__ float wmax(float v) {
    #pragma unroll
    for (int m = 1; m < 64; m <<= 1) v = fmaxf(v, __shfl_xor(v, m, 64));
    return v;
}

__device__ __forceinline__ void gh_row(int r, int lane,
    const float4* h4, const float* w_hh, const float* b_hh, float* gh)
{
    const float4* Wr = reinterpret_cast<const float4*>(w_hh + (size_t)r * H);
    float acc = 0.f;
    #pragma unroll
    for (int i = lane; i < H / 4; i += 64) acc = dot4(Wr[i], h4[i], acc);
    acc = wsum(acc);
    if (lane == 0) cstore(&gh[r], acc + b_hh[r]);
}

__global__ __launch_bounds__(256, 2) void fused_decoder(
    const float* __restrict__ input, const float* __restrict__ hidden,
    const float* __restrict__ enc,
    const float* __restrict__ attn_W, const float* __restrict__ attn_b,
    const float* __restrict__ comb_W, const float* __restrict__ comb_b,
    const float* __restrict__ w_ih, const float* __restrict__ w_hh,
    const float* __restrict__ b_ih, const float* __restrict__ b_hh,
    float* __restrict__ out, float* __restrict__ ws)
{
    __shared__ __align__(16) float sh[2048];
    __shared__ float smax[4], ssum[4];
    __shared__ float part[8][32];

    float* logits = ws;
    float* gh     = ws + OFF_GH;
    float* g      = ws + OFF_G;
    float* ctx    = ws + OFF_CTX;
    unsigned* cnt = (unsigned*)(ws + OFF_CNT);

    const int b = blockIdx.x, tid = threadIdx.x;
    const int wv = tid >> 6, lane = tid & 63;
    const float4* x4 = reinterpret_cast<const float4*>(input);
    const float4* h4 = reinterpret_cast<const float4*>(hidden);

    if (b < NLOG) {
        // ---- logits first (critical path): 1 row per wave ----
        const int r = b * 4 + wv;
        if (r < L) {
            const float4* Wr = reinterpret_cast<const float4*>(attn_W + (size_t)r * (2 * H));
            float acc = 0.f;
            #pragma unroll
            for (int i = lane; i < H / 4; i += 64) {
                acc = dot4(Wr[i], x4[i], acc);
                acc = dot4(Wr[H / 4 + i], h4[i], acc);
            }
            acc = wsum(acc);
            if (lane == 0) cstore(&logits[r], acc + attn_b[r]);
        }
        VMCNT0();
        __syncthreads();
        if (tid == 0) post(&cnt[C_LOG]);
        // ---- gh share: rows 5912 + b*3 .. +3 (capped) ----
        const int gb = 5912 + b * 3;
        for (int k = wv; k < 3; k += 4) {
            const int r2 = gb + k;
            if (r2 < 3 * H) gh_row(r2, lane, h4, w_hh, b_hh, gh);
        }
        VMCNT0();
        __syncthreads();
        if (tid == 0) post(&cnt[C_GH]);
    } else if (b < NLOG + NCTX) {
        const int cb = b - NLOG;
        // ---- gh share first (overlaps logits): rows 5400 + cb*8 .. +8 ----
        const int gb = 5400 + cb * 8;
        for (int k = wv; k < 8; k += 4) gh_row(gb + k, lane, h4, w_hh, b_hh, gh);
        VMCNT0();
        __syncthreads();
        if (tid == 0) post(&cnt[C_GH]);
        // ---- wait logits, then softmax (block-local, deterministic) ----
        if (tid == 0) {
            for (int it = 0; it < (1 << 22); ++it) {
                if (peek(&cnt[C_LOG]) >= NLOG) break;
                __builtin_amdgcn_s_sleep(8);
            }
        }
        __syncthreads();
        float v0 = (tid < L) ? cload(&logits[tid]) : -INFINITY;
        float v1 = (tid + 256 < L) ? cload(&logits[tid + 256]) : -INFINITY;
        float m = wmax(fmaxf(v0, v1));
        if (lane == 0) smax[wv] = m;
        __syncthreads();
        m = fmaxf(fmaxf(smax[0], smax[1]), fmaxf(smax[2], smax[3]));
        float e0 = (tid < L) ? expf(v0 - m) : 0.f;
        float e1 = (tid + 256 < L) ? expf(v1 - m) : 0.f;
        float s = wsum(e0 + e1);
        if (lane == 0) ssum[wv] = s;
        __syncthreads();
        const float inv = 1.f / (ssum[0] + ssum[1] + ssum[2] + ssum[3]);
        if (tid < L) sh[tid] = e0 * inv;
        if (tid + 256 < L) sh[tid + 256] = e1 * inv;
        if (cb == 0) {                    // attn_weights output
            if (tid < L) out[2 * H + tid] = e0 * inv;
            if (tid + 256 < L) out[2 * H + tid + 256] = e1 * inv;
        }
        __syncthreads();
        // ---- ctx: 32 cols, 8-way row split, 4-deep ILP ----
        const int col_l = tid & 31, k = tid >> 5;
        const float* ec = enc + cb * 32 + col_l;
        float a0 = 0.f, a1 = 0.f, a2 = 0.f, a3 = 0.f;
        int j = k;
        for (; j + 24 < L; j += 32) {
            a0 = fmaf(sh[j],      ec[(size_t)j * H],        a0);
            a1 = fmaf(sh[j + 8],  ec[(size_t)(j + 8) * H],  a1);
            a2 = fmaf(sh[j + 16], ec[(size_t)(j + 16) * H], a2);
            a3 = fmaf(sh[j + 24], ec[(size_t)(j + 24) * H], a3);
        }
        for (; j < L; j += 8) a0 = fmaf(sh[j], ec[(size_t)j * H], a0);
        part[k][col_l] = (a0 + a1) + (a2 + a3);
        __syncthreads();
        if (tid < 32) {
            float acc = 0.f;
            #pragma unroll
            for (int kk = 0; kk < 8; ++kk) acc += part[kk][tid];
            cstore(&ctx[cb * 32 + tid], acc);
        }
        VMCNT0();
        __syncthreads();
        if (tid == 0) post(&cnt[C_CTX]);
    } else {
        // ---- main gh blocks: rows (b-152)*15 .. +15 ----
        const int gb = (b - (NLOG + NCTX)) * 15;
        for (int k = wv; k < 15; k += 4) gh_row(gb + k, lane, h4, w_hh, b_hh, gh);
        VMCNT0();
        __syncthreads();
        if (tid == 0) post(&cnt[C_GH]);
    }

    // ================= combine: wait ctx, stage, 4 rows/block ==============
    if (tid == 0) {
        for (int it = 0; it < (1 << 22); ++it) {
            if (peek(&cnt[C_CTX]) >= NCTX) break;
            __builtin_amdgcn_s_sleep(16);
        }
    }
    __syncthreads();
    {
        unsigned long long* sh64 = reinterpret_cast<unsigned long long*>(sh);
        const unsigned long long* ctx64 = reinterpret_cast<const unsigned long long*>(ctx);
        for (int i = tid; i < H / 2; i += 256) sh64[i] = cload64(&ctx64[i]);
    }
    __syncthreads();
    {
        const float4* c4 = reinterpret_cast<const float4*>(sh);
        const int r = b * 4 + wv;
        const float4* Wr = reinterpret_cast<const float4*>(comb_W + (size_t)r * (2 * H));
        float acc = 0.f;
        #pragma unroll
        for (int i = lane; i < H / 4; i += 64) {
            acc = dot4(Wr[i], x4[i], acc);
            acc = dot4(Wr[H / 4 + i], c4[i], acc);
        }
        acc = wsum(acc);
        if (lane == 0) cstore(&g[r], fmaxf(acc + comb_b[r], 0.f));
        VMCNT0();
        __syncthreads();
        if (tid == 0) post(&cnt[C_CMB]);
    }

    // ================= GRU: wait cmb+gh, stage g, 4 cols/block =============
    if (tid == 0) {
        for (int it = 0; it < (1 << 22); ++it) {
            if (peek(&cnt[C_CMB]) >= NB && peek(&cnt[C_GH]) >= NB) break;
            __builtin_amdgcn_s_sleep(16);
        }
    }
    __syncthreads();
    {
        unsigned long long* sh64 = reinterpret_cast<unsigned long long*>(sh);
        const unsigned long long* g64 = reinterpret_cast<const unsigned long long*>(g);
        for (int i = tid; i < H / 2; i += 256) sh64[i] = cload64(&g64[i]);
    }
    __syncthreads();
    {
        const float4* g4 = reinterpret_cast<const float4*>(sh);
        const int col = b * 4 + wv;
        const float4* Wr0 = reinterpret_cast<const float4*>(w_ih + (size_t)col * H);
        const float4* Wr1 = reinterpret_cast<const float4*>(w_ih + (size_t)(col + H) * H);
        const float4* Wr2 = reinterpret_cast<const float4*>(w_ih + (size_t)(col + 2 * H) * H);
        float ar = 0.f, az = 0.f, an = 0.f;
        #pragma unroll
        for (int i = lane; i < H / 4; i += 64) {
            const float4 gv = g4[i];
            ar = dot4(Wr0[i], gv, ar);
            az = dot4(Wr1[i], gv, az);
            an = dot4(Wr2[i], gv, an);
        }
        ar = wsum(ar); az = wsum(az); an = wsum(an);
        if (lane == 0) {
            const float ir  = ar + b_ih[col];
            const float iz  = az + b_ih[col + H];
            const float in_ = an + b_ih[col + 2 * H];
            const float hr = cload(&gh[col]);
            const float hz = cload(&gh[col + H]);
            const float hn = cload(&gh[col + 2 * H]);
            const float r = 1.f / (1.f + expf(-(ir + hr)));
            const float z = 1.f / (1.f + expf(-(iz + hz)));
            const float n = tanhf(in_ + r * hn);
            const float hnew = (1.f - z) * n + z * hidden[col];
            out[col] = hnew;
            out[H + col] = hnew;
        }
    }
}

extern "C" void kernel_launch(void* const* d_in, const int* in_sizes, int n_in,
                              void* d_out, int out_size, void* d_ws, size_t ws_size,
                              hipStream_t stream)
{
    const float* input  = (const float*)d_in[0];
    const float* hidden = (const float*)d_in[1];
    const float* enc    = (const float*)d_in[2];
    const float* attn_W = (const float*)d_in[3];
    const float* attn_b = (const float*)d_in[4];
    const float* comb_W = (const float*)d_in[5];
    const float* comb_b = (const float*)d_in[6];
    const float* w_ih   = (const float*)d_in[7];
    const float* w_hh   = (const float*)d_in[8];
    const float* b_ih   = (const float*)d_in[9];
    const float* b_hh   = (const float*)d_in[10];
    float* out = (float*)d_out;
    float* ws  = (float*)d_ws;

    // counters (4 slots x 256B) must start at zero
    hipMemsetAsync(ws + OFF_CNT, 0, 1024, stream);

    fused_decoder<<<NB, 256, 0, stream>>>(
        input, hidden, enc, attn_W, attn_b, comb_W, comb_b,
        w_ih, w_hh, b_ih, b_hh, out, ws);
}

// Round 10
// 36.654 us; speedup vs baseline: 3.7492x; 1.7652x over previous
//
#include <hip/hip_runtime.h>
#include <math.h>

#define H 2048
#define L 350
#define GH1 4096         // gh rows computed in K1; rest (2048) in K2

__device__ __forceinline__ float dot4(float4 a, float4 b, float acc) {
    acc = fmaf(a.x, b.x, acc);
    acc = fmaf(a.y, b.y, acc);
    acc = fmaf(a.z, b.z, acc);
    acc = fmaf(a.w, b.w, acc);
    return acc;
}

__device__ __forceinline__ float wsum(float v) {
    #pragma unroll
    for (int m = 1; m < 64; m <<= 1) v += __shfl_xor(v, m, 64);
    return v;
}
__device__ __forceinline__ float wmax(float v) {
    #pragma unroll
    for (int m = 1; m < 64; m <<= 1) v = fmaxf(v, __shfl_xor(v, m, 64));
    return v;
}

// gh row helper: gh[row] = h . w_hh[row] + b_hh[row], one wave
__device__ __forceinline__ void gh_row(int row, int lane,
    const float4* h4, const float* w_hh, const float* b_hh, float* gh)
{
    const float4* Wr = reinterpret_cast<const float4*>(w_hh + (size_t)row * H);
    float acc = 0.f;
    #pragma unroll
    for (int i = lane; i < H / 4; i += 64) acc = dot4(Wr[i], h4[i], acc);
    acc = wsum(acc);
    if (lane == 0) gh[row] = acc + b_hh[row];
}

// K1: waves 0..349: attn logits (16KB rows); waves 350..: gh rows [0,GH1)
__global__ __launch_bounds__(256) void k1_logits_gh(
    const float* __restrict__ input, const float* __restrict__ hidden,
    const float* __restrict__ attn_W, const float* __restrict__ attn_b,
    const float* __restrict__ w_hh, const float* __restrict__ b_hh,
    float* __restrict__ logits, float* __restrict__ gh)
{
    const int w = threadIdx.x >> 6, lane = threadIdx.x & 63;
    const int item = blockIdx.x * 4 + w;
    const float4* x4 = reinterpret_cast<const float4*>(input);
    const float4* h4 = reinterpret_cast<const float4*>(hidden);
    if (item < L) {
        const float4* Wr = reinterpret_cast<const float4*>(attn_W + (size_t)item * (2 * H));
        float acc = 0.f;
        #pragma unroll
        for (int i = lane; i < H / 4; i += 64) {
            acc = dot4(Wr[i], x4[i], acc);
            acc = dot4(Wr[H / 4 + i], h4[i], acc);
        }
        acc = wsum(acc);
        if (lane == 0) logits[item] = acc + attn_b[item];
    } else if (item < L + GH1) {
        gh_row(item - L, lane, h4, w_hh, b_hh, gh);
    }
}

// K2: blocks 0..63: softmax (redundant per block, deterministic) + 32 ctx cols;
//     blocks 64..575: gh rows [GH1, 6144)
__global__ __launch_bounds__(256) void k2_softmax_ctx_gh(
    const float* __restrict__ logits, const float* __restrict__ enc,
    const float* __restrict__ hidden,
    const float* __restrict__ w_hh, const float* __restrict__ b_hh,
    float* __restrict__ ctx, float* __restrict__ gh, float* __restrict__ attn_out)
{
    const int t = threadIdx.x, w = t >> 6, lane = t & 63;
    if (blockIdx.x >= 64) {
        const int row = GH1 + (blockIdx.x - 64) * 4 + w;
        gh_row(row, lane, reinterpret_cast<const float4*>(hidden), w_hh, b_hh, gh);
        return;
    }
    __shared__ float attn_s[L];
    __shared__ float smax[4], ssum[4];
    __shared__ float partial[8][32];

    float v0 = (t < L) ? logits[t] : -INFINITY;
    float v1 = (t + 256 < L) ? logits[t + 256] : -INFINITY;
    float m = wmax(fmaxf(v0, v1));
    if (lane == 0) smax[w] = m;
    __syncthreads();
    m = fmaxf(fmaxf(smax[0], smax[1]), fmaxf(smax[2], smax[3]));
    float e0 = (t < L) ? expf(v0 - m) : 0.f;
    float e1 = (t + 256 < L) ? expf(v1 - m) : 0.f;
    float s = wsum(e0 + e1);
    if (lane == 0) ssum[w] = s;
    __syncthreads();
    const float inv = 1.f / (ssum[0] + ssum[1] + ssum[2] + ssum[3]);
    if (t < L) attn_s[t] = e0 * inv;
    if (t + 256 < L) attn_s[t + 256] = e1 * inv;
    if (blockIdx.x == 0) {
        if (t < L) attn_out[t] = e0 * inv;
        if (t + 256 < L) attn_out[t + 256] = e1 * inv;
    }
    __syncthreads();

    // ctx: col = blockIdx*32 + (t&31); 8-way row split (k = t>>5), 4-deep ILP
    const int col_l = t & 31, k = t >> 5;
    const int col = blockIdx.x * 32 + col_l;
    const float* ec = enc + col;
    float a0 = 0.f, a1 = 0.f, a2 = 0.f, a3 = 0.f;
    int j = k;
    for (; j + 24 < L; j += 32) {
        a0 = fmaf(attn_s[j],      ec[(size_t)j * H],        a0);
        a1 = fmaf(attn_s[j + 8],  ec[(size_t)(j + 8) * H],  a1);
        a2 = fmaf(attn_s[j + 16], ec[(size_t)(j + 16) * H], a2);
        a3 = fmaf(attn_s[j + 24], ec[(size_t)(j + 24) * H], a3);
    }
    for (; j < L; j += 8) a0 = fmaf(attn_s[j], ec[(size_t)j * H], a0);
    partial[k][col_l] = (a0 + a1) + (a2 + a3);
    __syncthreads();
    if (t < 32) {
        float acc = 0.f;
        #pragma unroll
        for (int kk = 0; kk < 8; ++kk) acc += partial[kk][t];
        ctx[blockIdx.x * 32 + t] = acc;
    }
}

// K3: one block per combine row. 256 threads x 4 float4 = 4096 floats (row).
__global__ __launch_bounds__(256) void k3_combine(
    const float* __restrict__ input, const float* __restrict__ ctx,
    const float* __restrict__ comb_W, const float* __restrict__ comb_b,
    float* __restrict__ g)
{
    __shared__ float red[4];
    const int t = threadIdx.x, wv = t >> 6, lane = t & 63;
    const int r = blockIdx.x;
    const float4* x4 = reinterpret_cast<const float4*>(input);
    const float4* c4 = reinterpret_cast<const float4*>(ctx);
    const float4* Wr = reinterpret_cast<const float4*>(comb_W + (size_t)r * (2 * H));
    float acc = dot4(Wr[t], x4[t], 0.f);
    acc = dot4(Wr[t + 256], x4[t + 256], acc);
    acc = dot4(Wr[t + 512], c4[t], acc);
    acc = dot4(Wr[t + 768], c4[t + 256], acc);
    acc = wsum(acc);
    if (lane == 0) red[wv] = acc;
    __syncthreads();
    if (t == 0)
        g[r] = fmaxf(red[0] + red[1] + red[2] + red[3] + comb_b[r], 0.f);
}

// K4: one block per GRU column. 3 w_ih rows (8KB each) + gates.
__global__ __launch_bounds__(256) void k4_gru(
    const float* __restrict__ g, const float* __restrict__ hidden,
    const float* __restrict__ w_ih, const float* __restrict__ b_ih,
    const float* __restrict__ gh, float* __restrict__ out)
{
    __shared__ float part[4][3];
    const int t = threadIdx.x, wv = t >> 6, lane = t & 63;
    const int c = blockIdx.x;
    const float4* g4  = reinterpret_cast<const float4*>(g);
    const float4* W0 = reinterpret_cast<const float4*>(w_ih + (size_t)c * H);
    const float4* W1 = reinterpret_cast<const float4*>(w_ih + (size_t)(c + H) * H);
    const float4* W2 = reinterpret_cast<const float4*>(w_ih + (size_t)(c + 2 * H) * H);
    const float4 gv0 = g4[t], gv1 = g4[t + 256];
    float ar = dot4(W0[t], gv0, 0.f); ar = dot4(W0[t + 256], gv1, ar);
    float az = dot4(W1[t], gv0, 0.f); az = dot4(W1[t + 256], gv1, az);
    float an = dot4(W2[t], gv0, 0.f); an = dot4(W2[t + 256], gv1, an);
    ar = wsum(ar); az = wsum(az); an = wsum(an);
    if (lane == 0) { part[wv][0] = ar; part[wv][1] = az; part[wv][2] = an; }
    __syncthreads();
    if (t == 0) {
        const float ir  = part[0][0] + part[1][0] + part[2][0] + part[3][0] + b_ih[c];
        const float iz  = part[0][1] + part[1][1] + part[2][1] + part[3][1] + b_ih[c + H];
        const float in_ = part[0][2] + part[1][2] + part[2][2] + part[3][2] + b_ih[c + 2 * H];
        const float r = 1.f / (1.f + expf(-(ir + gh[c])));
        const float z = 1.f / (1.f + expf(-(iz + gh[c + H])));
        const float n = tanhf(in_ + r * gh[c + 2 * H]);
        const float hnew = (1.f - z) * n + z * hidden[c];
        out[c] = hnew;
        out[H + c] = hnew;
    }
}

extern "C" void kernel_launch(void* const* d_in, const int* in_sizes, int n_in,
                              void* d_out, int out_size, void* d_ws, size_t ws_size,
                              hipStream_t stream)
{
    const float* input  = (const float*)d_in[0];
    const float* hidden = (const float*)d_in[1];
    const float* enc    = (const float*)d_in[2];
    const float* attn_W = (const float*)d_in[3];
    const float* attn_b = (const float*)d_in[4];
    const float* comb_W = (const float*)d_in[5];
    const float* comb_b = (const float*)d_in[6];
    const float* w_ih   = (const float*)d_in[7];
    const float* w_hh   = (const float*)d_in[8];
    const float* b_ih   = (const float*)d_in[9];
    const float* b_hh   = (const float*)d_in[10];
    float* out = (float*)d_out;
    float* ws  = (float*)d_ws;

    float* logits = ws;            // 350
    float* gh     = ws + 512;      // 6144
    float* g      = ws + 7168;     // 2048
    float* ctx    = ws + 9216;     // 2048

    k1_logits_gh<<<(L + GH1 + 3) / 4, 256, 0, stream>>>(
        input, hidden, attn_W, attn_b, w_hh, b_hh, logits, gh);
    k2_softmax_ctx_gh<<<64 + (3 * H - GH1) / 4, 256, 0, stream>>>(
        logits, enc, hidden, w_hh, b_hh, ctx, gh, out + 2 * H);
    k3_combine<<<H, 256, 0, stream>>>(input, ctx, comb_W, comb_b, g);
    k4_gru<<<H, 256, 0, stream>>>(g, hidden, w_ih, b_ih, gh, out);
}